// Round 17
// baseline (1366.894 us; speedup 1.0000x reference)
//
#include <hip/hip_runtime.h>
#include <hip/hip_bf16.h>

typedef __hip_bfloat16 bf16;
typedef float f32x4 __attribute__((ext_vector_type(4)));
typedef float f32x16 __attribute__((ext_vector_type(16)));
typedef short s16x8 __attribute__((ext_vector_type(8)));
typedef int i32x4 __attribute__((ext_vector_type(4)));
typedef unsigned u32x2 __attribute__((ext_vector_type(2)));

#define S_LEN 1024
#define BATCH 2
#define TDIM 138
#define KPAD 192
#define DMOD 1024
#define NHEAD 16
#define DHEAD 64
#define NLAYER 8
#define FDIM 2048
#define MROWS 2048
#define NITEM 80             // flash items per bh (256-key chunks)
static const size_t DD_ = (size_t)DMOD * DMOD;   // 1M elems
static const size_t FD_ = (size_t)FDIM * DMOD;   // 2M elems
static const size_t LW_ = 4 * DD_ + 2 * FD_;     // 8M elems per layer

__device__ __forceinline__ void load_lds16(const bf16* g, bf16* l) {
  __builtin_amdgcn_global_load_lds((const __attribute__((address_space(1))) void*)g,
                                   (__attribute__((address_space(3))) void*)l, 16, 0, 0);
}

__device__ __forceinline__ unsigned pack2(float a, float b) {
  unsigned x = __builtin_bit_cast(unsigned short, __float2bfloat16(a));
  unsigned y = __builtin_bit_cast(unsigned short, __float2bfloat16(b));
  return x | (y << 16);
}

__device__ __forceinline__ float b2f(unsigned short u) {
  return __bfloat162float(__builtin_bit_cast(bf16, u));
}

__device__ __forceinline__ int chunk_start(int c) {
  return c == 0 ? 0 : (c == 1 ? 32 : (c == 2 ? 56 : 72));
}

// ---------------- weight f32 -> bf16, block-uniform chunk decode (no per-iter div) ----------------
// nchunk = 8*nlay chunks of DD_/4 float4 each (per layer: Wq,Wk,Wv,Wo,W1a,W1b,W2a,W2b).
__global__ __launch_bounds__(256) void f2b_all(
    const float4* __restrict__ Wq, const float4* __restrict__ Wk,
    const float4* __restrict__ Wv, const float4* __restrict__ Wo,
    const float4* __restrict__ W1, const float4* __restrict__ W2,
    ushort4* __restrict__ dst, int nlay) {
  const int DD4 = (int)(DD_ / 4), FD4 = (int)(FD_ / 4), LW4 = 4 * DD4 + 2 * FD4;
  int nchunk = 8 * nlay;
  int bpc = gridDim.x / nchunk;             // blocks per chunk (grid divisible)
  int elems = DD4 / bpc;                    // float4 per block
  int chunk = blockIdx.x / bpc;
  int bic = blockIdx.x - chunk * bpc;       // block index within chunk
  int l = chunk >> 3, k = chunk & 7;
  const float4* src;
  int soff, doff;
  if (k < 4) {
    src = k == 0 ? Wq : (k == 1 ? Wk : (k == 2 ? Wv : Wo));
    soff = l * DD4;
    doff = l * LW4 + k * DD4;
  } else if (k < 6) {
    src = W1;
    soff = l * FD4 + (k - 4) * DD4;
    doff = l * LW4 + 4 * DD4 + (k - 4) * DD4;
  } else {
    src = W2;
    soff = l * FD4 + (k - 6) * DD4;
    doff = l * LW4 + 4 * DD4 + FD4 + (k - 6) * DD4;
  }
  int base = bic * elems;
  const float4* s = src + soff + base;
  ushort4* d = dst + doff + base;
#pragma unroll 4
  for (int i = threadIdx.x; i < elems; i += 256) {
    float4 v = s[i];
    ushort4 o;
    o.x = __builtin_bit_cast(unsigned short, __float2bfloat16(v.x));
    o.y = __builtin_bit_cast(unsigned short, __float2bfloat16(v.y));
    o.z = __builtin_bit_cast(unsigned short, __float2bfloat16(v.z));
    o.w = __builtin_bit_cast(unsigned short, __float2bfloat16(v.w));
    d[i] = o;
  }
}

// ---------------- pad+convert a row-major f32 [R][TDIM] -> bf16 [R][KPAD] ----------------
__global__ __launch_bounds__(256) void pad_cvt(const float* __restrict__ in,
                                               bf16* __restrict__ out, int R) {
  int i = blockIdx.x * 256 + threadIdx.x;
  if (i >= R * KPAD) return;
  int r = i / KPAD, t = i - r * KPAD;
  out[i] = __float2bfloat16(t < TDIM ? in[r * TDIM + t] : 0.0f);
}

// ---------------- rope table ----------------
__global__ __launch_bounds__(256) void rope_table(float2* __restrict__ t) {
  int idx = blockIdx.x * 256 + threadIdx.x;
  if (idx >= S_LEN * 32) return;
  int s = idx >> 5, i = idx & 31;
  float freq = __expf(-(float)i * (2.0f / (float)DHEAD) * 9.210340371976184f);
  float sn, cs;
  sincosf((float)s * freq, &sn, &cs);
  t[idx] = make_float2(cs, sn);
}

// ---------------- 64x128 NT GEMM: BK=64, XOR-swizzled LDS, 2-phase dbuf ----------------
template<int EPI, int SPLITK>
__global__ __launch_bounds__(256) void gemm64(
    const bf16* __restrict__ A, const bf16* __restrict__ W,
    const float* __restrict__ b0p, const float* __restrict__ b1p, const float* __restrict__ b2p,
    const float2* __restrict__ rope2, float* __restrict__ Cf,
    bf16* __restrict__ Cb0, bf16* __restrict__ Cb1, bf16* __restrict__ Cb2,
    int N, int K, int nby) {
  constexpr int ASZ = 64 * 64, BSZ = 128 * 64;
  __shared__ bf16 As[2 * ASZ];    // 16 KB
  __shared__ bf16 Bs[2 * BSZ];    // 32 KB
  int nwg = gridDim.x, bid = blockIdx.x;
  int x = bid & 7, c = bid >> 3;                  // XCD, per-XCD index
  int chunkSz = nwg >> 3;
  int bxc = chunkSz / nby;                        // bx2 values per XCD
  int per = 8 * bxc;                              // blocks per by-group stripe
  int grp = c / per, r0_ = c - grp * per;
  int bxl = r0_ >> 3, byg = r0_ & 7;
  int by = grp * 8 + byg;
  int bx2 = x * bxc + bxl;
  int nbx = N >> 7;
  int kh = 0, bx = bx2;
  if constexpr (SPLITK == 2) { bx = bx2 % nbx; kh = bx2 / nbx; }
  int bn = bx * 128, bm = by * 64;
  int Kh = K / SPLITK, koff = kh * Kh;
  int tid = threadIdx.x, lane = tid & 63, w = tid >> 6;
  int lo = lane & 15, hi = lane >> 4;
  int wr = (w >> 1) * 32, wc = (w & 1) * 64;
  f32x4 acc[2][4] = {};

  int srow = tid >> 3;                  // 0..31
  int scol = (tid & 7) * 8;             // elems, 16B chunks
  int scolsw = scol ^ ((srow & 7) << 3);
  const bf16* gA = A + (size_t)(bm + srow) * K + koff + scolsw;
  const bf16* gB = W + (size_t)(bn + srow) * K + koff + scolsw;
  bf16* lA = As + srow * 64 + scol;
  bf16* lB = Bs + srow * 64 + scol;

  auto STAGE = [&](int k0, int b) {
    load_lds16(gA + k0, lA + b * ASZ);
    load_lds16(gA + (size_t)32 * K + k0, lA + b * ASZ + 32 * 64);
    load_lds16(gB + k0, lB + b * BSZ);
    load_lds16(gB + (size_t)32 * K + k0, lB + b * BSZ + 32 * 64);
    load_lds16(gB + (size_t)64 * K + k0, lB + b * BSZ + 64 * 64);
    load_lds16(gB + (size_t)96 * K + k0, lB + b * BSZ + 96 * 64);
  };

  int nt = Kh / 64;
  STAGE(0, 0);
  __syncthreads();
  int cur = 0;
  int rsw = (lo & 7) << 3;              // ds_read swizzle term (row&7 == lo&7)
  for (int t = 0; t < nt; t++) {
    if (t + 1 < nt) STAGE((t + 1) * 64, cur ^ 1);
    const bf16* Ab = As + cur * ASZ;
    const bf16* Bb = Bs + cur * BSZ;
#pragma unroll
    for (int ks = 0; ks < 2; ks++) {
      int col = ((ks * 32 + hi * 8) ^ rsw);
      s16x8 af[2], bfr[4];
#pragma unroll
      for (int mi = 0; mi < 2; mi++) af[mi] = *(const s16x8*)(Ab + (wr + mi * 16 + lo) * 64 + col);
#pragma unroll
      for (int nj = 0; nj < 4; nj++) bfr[nj] = *(const s16x8*)(Bb + (wc + nj * 16 + lo) * 64 + col);
#pragma unroll
      for (int mi = 0; mi < 2; mi++)
#pragma unroll
        for (int nj = 0; nj < 4; nj++)
          acc[mi][nj] = __builtin_amdgcn_mfma_f32_16x16x32_bf16(af[mi], bfr[nj], acc[mi][nj], 0, 0, 0);
    }
    __syncthreads();
    cur ^= 1;
  }

#pragma unroll
  for (int mi = 0; mi < 2; mi++)
#pragma unroll
    for (int nj = 0; nj < 4; nj++)
#pragma unroll
      for (int r = 0; r < 4; r++) {
        int m = bm + wr + mi * 16 + hi * 4 + r;
        int n = bn + wc + nj * 16 + lo;
        float v = acc[mi][nj][r];
        if constexpr (EPI == 0) {
          int which = n >> 10;
          int d = n & 1023, h = d >> 6, dh = d & 63;
          int s = m >> 1, bb = m & 1;
          const float* bp = which == 0 ? b0p : (which == 1 ? b1p : b2p);
          v += bp[d];
          if (which < 2) {
            float pv = __shfl_xor(v, 1);
            float2 cn = rope2[s * 32 + (dh >> 1)];
            float o = (dh & 1) ? (v * cn.x + pv * cn.y) : (v * cn.x - pv * cn.y);
            bf16* dst = which == 0 ? Cb0 : Cb1;
            dst[(((size_t)(bb * NHEAD + h)) * S_LEN + s) * DHEAD + dh] = __float2bfloat16(o);
          } else {
            Cb2[(((size_t)(bb * NHEAD + h)) * DHEAD + dh) * S_LEN + s] = __float2bfloat16(v);
          }
        } else if constexpr (EPI == 1) {
          if (SPLITK == 1 || kh == 0) v += b0p[n];
          Cb0[((size_t)kh * MROWS + m) * N + n] = __float2bfloat16(v);
        } else if constexpr (EPI == 2) {
          Cb0[(size_t)m * N + n] = __float2bfloat16(fmaxf(v + b0p[n], 0.0f));
        } else {
          float v2 = v + b0p[n] + b1p[(size_t)(m >> 1) * DMOD + n];
          Cf[(size_t)m * N + n] = v2;
          Cb0[(size_t)m * N + n] = __float2bfloat16(v2);
        }
      }
}

// ---------------- split-K flash attention, 32x32 MFMA, XCD-affine, 256-key chunks ----------------
__global__ __launch_bounds__(256) void flash_part(const bf16* __restrict__ Q,
    const bf16* __restrict__ K, const bf16* __restrict__ Vt,
    bf16* __restrict__ pO, float* __restrict__ pML, bf16* __restrict__ O) {
  int bid = blockIdx.x;                    // 640 = 8 xcd * 4 bh * 20 blocks
  int xcd = bid & 7, idx = bid >> 3;       // idx in [0,80)
  int bh = xcd * 4 + idx / 20;
  int w = threadIdx.x >> 6, lane = threadIdx.x & 63;
  int widx = (idx % 20) * 4 + w;           // item in [0,80)
  int c = widx < 32 ? 0 : (widx < 56 ? 1 : (widx < 72 ? 2 : 3));
  int qt = widx - chunk_start(c) + 8 * c;  // q-tile [0,32)
  int l31 = lane & 31, hi1 = lane >> 5;
  int q0 = qt * 32, kc0 = c * 256;
  int kend = min(kc0 + 256, q0 + 32);
  int nkt = (kend - kc0 + 31) >> 5;        // 1..8

  const size_t qkb = (size_t)bh * S_LEN * DHEAD;
  const bf16* qp = Q + qkb + (size_t)(q0 + l31) * DHEAD + hi1 * 8;
  s16x8 bq0 = *(const s16x8*)(qp);
  s16x8 bq1 = *(const s16x8*)(qp + 16);
  s16x8 bq2 = *(const s16x8*)(qp + 32);
  s16x8 bq3 = *(const s16x8*)(qp + 48);
  const bf16* kB = K + qkb;
  const bf16* vB = Vt + qkb;
  f32x16 accO0 = {}, accO1 = {};
  float mv = -INFINITY, lv = 0.0f;
  const float SC = 0.18033688011112042f;   // (1/8) * log2(e)

  auto loadTile = [&](int kc, s16x8& k0, s16x8& k1, s16x8& k2, s16x8& k3,
                      s16x8& v0, s16x8& v1, s16x8& v2, s16x8& v3) {
    const bf16* kp = kB + (size_t)(kc + l31) * DHEAD + hi1 * 8;
    k0 = *(const s16x8*)(kp);
    k1 = *(const s16x8*)(kp + 16);
    k2 = *(const s16x8*)(kp + 32);
    k3 = *(const s16x8*)(kp + 48);
    const bf16* vp = vB + (size_t)l31 * S_LEN + kc + hi1 * 8;
    v0 = *(const s16x8*)(vp);
    v1 = *(const s16x8*)(vp + 16);
    v2 = *(const s16x8*)(vp + (size_t)32 * S_LEN);
    v3 = *(const s16x8*)(vp + (size_t)32 * S_LEN + 16);
  };

  auto computeTile = [&](int kc, s16x8 ka0, s16x8 ka1, s16x8 ka2, s16x8 ka3,
                         s16x8 va00, s16x8 va01, s16x8 va10, s16x8 va11) {
    f32x16 st = {};
    st = __builtin_amdgcn_mfma_f32_32x32x16_bf16(ka0, bq0, st, 0, 0, 0);
    st = __builtin_amdgcn_mfma_f32_32x32x16_bf16(ka1, bq1, st, 0, 0, 0);
    st = __builtin_amdgcn_mfma_f32_32x32x16_bf16(ka2, bq2, st, 0, 0, 0);
    st = __builtin_amdgcn_mfma_f32_32x32x16_bf16(ka3, bq3, st, 0, 0, 0);

    bool diag = (kc >= q0);                // wave-uniform
    float pmax = -INFINITY;
#pragma unroll
    for (int j = 0; j < 16; j++) {
      float s = st[j] * SC;
      if (diag) {
        int krow = kc + (j & 3) + 8 * (j >> 2) + 4 * hi1;
        if (krow > q0 + l31) s = -INFINITY;
      }
      st[j] = s;
      pmax = fmaxf(pmax, s);
    }
    pmax = fmaxf(pmax, __shfl_xor(pmax, 32));
    float mnew = fmaxf(mv, pmax);
    float fs = exp2f(mv - mnew);
    float sum = 0.0f;
#pragma unroll
    for (int j = 0; j < 16; j++) {
      float e = exp2f(st[j] - mnew);
      st[j] = e;
      sum += e;
    }
    sum += __shfl_xor(sum, 32);
    lv = lv * fs + sum;
    mv = mnew;
    accO0 = accO0 * fs;
    accO1 = accO1 * fs;

    unsigned w0 = pack2(st[0], st[1]),   w1 = pack2(st[2], st[3]);
    unsigned w2 = pack2(st[4], st[5]),   w3 = pack2(st[6], st[7]);
    unsigned w4 = pack2(st[8], st[9]),   w5 = pack2(st[10], st[11]);
    unsigned w6 = pack2(st[12], st[13]), w7 = pack2(st[14], st[15]);
    unsigned xw0 = (unsigned)__shfl_xor((int)w0, 32), xw1 = (unsigned)__shfl_xor((int)w1, 32);
    unsigned xw2 = (unsigned)__shfl_xor((int)w2, 32), xw3 = (unsigned)__shfl_xor((int)w3, 32);
    unsigned xw4 = (unsigned)__shfl_xor((int)w4, 32), xw5 = (unsigned)__shfl_xor((int)w5, 32);
    unsigned xw6 = (unsigned)__shfl_xor((int)w6, 32), xw7 = (unsigned)__shfl_xor((int)w7, 32);
    bool hb = (hi1 != 0);
    i32x4 f0, f1;
    f0.x = (int)(hb ? xw2 : w0); f0.y = (int)(hb ? xw3 : w1);
    f0.z = (int)(hb ? w2 : xw0); f0.w = (int)(hb ? w3 : xw1);
    f1.x = (int)(hb ? xw6 : w4); f1.y = (int)(hb ? xw7 : w5);
    f1.z = (int)(hb ? w6 : xw4); f1.w = (int)(hb ? w7 : xw5);
    s16x8 pf0 = __builtin_bit_cast(s16x8, f0);
    s16x8 pf1 = __builtin_bit_cast(s16x8, f1);
    accO0 = __builtin_amdgcn_mfma_f32_32x32x16_bf16(va00, pf0, accO0, 0, 0, 0);
    accO0 = __builtin_amdgcn_mfma_f32_32x32x16_bf16(va01, pf1, accO0, 0, 0, 0);
    accO1 = __builtin_amdgcn_mfma_f32_32x32x16_bf16(va10, pf0, accO1, 0, 0, 0);
    accO1 = __builtin_amdgcn_mfma_f32_32x32x16_bf16(va11, pf1, accO1, 0, 0, 0);
  };

  // 2-deep register pipeline: named sets, unroll-2 rotation (static indexing)
  s16x8 A0, A1, A2, A3, A4, A5, A6, A7;
  s16x8 B0, B1, B2, B3, B4, B5, B6, B7;
  loadTile(kc0, A0, A1, A2, A3, A4, A5, A6, A7);
  for (int kt = 0; kt < nkt; kt += 2) {
    if (kt + 1 < nkt) loadTile(kc0 + (kt + 1) * 32, B0, B1, B2, B3, B4, B5, B6, B7);
    computeTile(kc0 + kt * 32, A0, A1, A2, A3, A4, A5, A6, A7);
    if (kt + 1 < nkt) {
      if (kt + 2 < nkt) loadTile(kc0 + (kt + 2) * 32, A0, A1, A2, A3, A4, A5, A6, A7);
      computeTile(kc0 + (kt + 1) * 32, B0, B1, B2, B3, B4, B5, B6, B7);
    }
  }

  if (widx < 8) {
    // single-chunk item: write normalized O directly, skip partials+merge
    int b = bh >> 4, h = bh & 15;
    float linv = 1.0f / lv;
    bf16* po = O + ((size_t)(q0 + l31) * BATCH + b) * DMOD + h * DHEAD + 4 * hi1;
#pragma unroll
    for (int jj = 0; jj < 4; jj++) {
      u32x2 v0, v1;
      v0.x = pack2(accO0[4 * jj] * linv, accO0[4 * jj + 1] * linv);
      v0.y = pack2(accO0[4 * jj + 2] * linv, accO0[4 * jj + 3] * linv);
      v1.x = pack2(accO1[4 * jj] * linv, accO1[4 * jj + 1] * linv);
      v1.y = pack2(accO1[4 * jj + 2] * linv, accO1[4 * jj + 3] * linv);
      *(u32x2*)(po + 8 * jj) = v0;
      *(u32x2*)(po + 32 + 8 * jj) = v1;
    }
  } else {
    int pbase = bh * NITEM + widx;
    bf16* po = pO + (size_t)pbase * 2048 + l31 * 64 + 4 * hi1;
#pragma unroll
    for (int jj = 0; jj < 4; jj++) {
      u32x2 v0, v1;
      v0.x = pack2(accO0[4 * jj], accO0[4 * jj + 1]);
      v0.y = pack2(accO0[4 * jj + 2], accO0[4 * jj + 3]);
      v1.x = pack2(accO1[4 * jj], accO1[4 * jj + 1]);
      v1.y = pack2(accO1[4 * jj + 2], accO1[4 * jj + 3]);
      *(u32x2*)(po + 8 * jj) = v0;
      *(u32x2*)(po + 32 + 8 * jj) = v1;
    }
    if (hi1 == 0) {
      pML[pbase * 64 + l31] = mv;
      pML[pbase * 64 + 32 + l31] = lv;
    }
  }
}

// ---------------- split-K flash attention, merge (qt in [8,32) only) ----------------
__global__ __launch_bounds__(256) void flash_merge(const bf16* __restrict__ pO,
    const float* __restrict__ pML, bf16* __restrict__ O) {
  int bid = blockIdx.x;                    // 768 = 8 xcd * 4 bh * 24 qt
  int xcd = bid & 7, idx = bid >> 3;
  int bh = xcd * 4 + idx / 24, qt = idx % 24 + 8;
  int b = bh >> 4, h = bh & 15;
  int nch = (qt >> 3) + 1;                 // chunk c serves qt >= 8c
  int t = threadIdx.x;
  int dh = t & 63, r0 = t >> 6;
  int ibase = bh * NITEM;
#pragma unroll
  for (int j = 0; j < 8; j++) {
    int row = j * 4 + r0;
    float ms = -INFINITY;
    for (int cc = 0; cc < nch; cc++) {
      int wi = chunk_start(cc) + qt - 8 * cc;
      ms = fmaxf(ms, pML[(ibase + wi) * 64 + row]);
    }
    float l = 0.0f, o = 0.0f;
    for (int cc = 0; cc < nch; cc++) {
      int wi = chunk_start(cc) + qt - 8 * cc;
      float wgt = exp2f(pML[(ibase + wi) * 64 + row] - ms);
      l += wgt * pML[(ibase + wi) * 64 + 32 + row];
      o += wgt * __bfloat162float(pO[(size_t)(ibase + wi) * 2048 + row * 64 + dh]);
    }
    int q = qt * 32 + row;
    O[((size_t)q * BATCH + b) * DMOD + h * DHEAD + dh] = __float2bfloat16(o / l);
  }
}

// ---------------- LayerNorm(a + r0 + r1) * g + be -> outf/outb (vectorized) ----------------
__global__ __launch_bounds__(256) void ln_kernel(const float* __restrict__ a,
    const bf16* __restrict__ r0, const bf16* __restrict__ r1,
    const float* __restrict__ g, const float* __restrict__ be,
    float* __restrict__ outf, bf16* __restrict__ outb) {
  int m = blockIdx.x;
  int tid = threadIdx.x;
  int d0 = tid * 4;
  size_t base = (size_t)m * DMOD + d0;
  f32x4 av = *(const f32x4*)(a + base);
  ushort4 u0 = *(const ushort4*)(r0 + base);
  ushort4 u1 = *(const ushort4*)(r1 + base);
  float vals[4];
  vals[0] = av[0] + b2f(u0.x) + b2f(u1.x);
  vals[1] = av[1] + b2f(u0.y) + b2f(u1.y);
  vals[2] = av[2] + b2f(u0.z) + b2f(u1.z);
  vals[3] = av[3] + b2f(u0.w) + b2f(u1.w);
  float s1 = vals[0] + vals[1] + vals[2] + vals[3];
  float s2 = vals[0]*vals[0] + vals[1]*vals[1] + vals[2]*vals[2] + vals[3]*vals[3];
  __shared__ float red[8];
  for (int d = 1; d < 64; d <<= 1) { s1 += __shfl_xor(s1, d); s2 += __shfl_xor(s2, d); }
  int w = tid >> 6, lane = tid & 63;
  if (lane == 0) { red[w] = s1; red[4 + w] = s2; }
  __syncthreads();
  s1 = red[0] + red[1] + red[2] + red[3];
  s2 = red[4] + red[5] + red[6] + red[7];
  float mean = s1 * (1.0f / DMOD);
  float var = s2 * (1.0f / DMOD) - mean * mean;
  float rstd = rsqrtf(var + 1e-5f);
  f32x4 gv = *(const f32x4*)(g + d0);
  f32x4 bv = *(const f32x4*)(be + d0);
  f32x4 ov;
  ushort4 ob_;
  float o0 = (vals[0] - mean) * rstd * gv[0] + bv[0];
  float o1 = (vals[1] - mean) * rstd * gv[1] + bv[1];
  float o2 = (vals[2] - mean) * rstd * gv[2] + bv[2];
  float o3 = (vals[3] - mean) * rstd * gv[3] + bv[3];
  ov[0] = o0; ov[1] = o1; ov[2] = o2; ov[3] = o3;
  ob_.x = __builtin_bit_cast(unsigned short, __float2bfloat16(o0));
  ob_.y = __builtin_bit_cast(unsigned short, __float2bfloat16(o1));
  ob_.z = __builtin_bit_cast(unsigned short, __float2bfloat16(o2));
  ob_.w = __builtin_bit_cast(unsigned short, __float2bfloat16(o3));
  *(f32x4*)(outf + base) = ov;
  *(ushort4*)(outb + base) = ob_;
}

// ---------------- head ----------------
__global__ __launch_bounds__(256) void head_kernel(const float* __restrict__ x,
    const float* __restrict__ Wh, const float* __restrict__ bh, float* __restrict__ out) {
  int m = blockIdx.x * 4 + (threadIdx.x >> 6);
  int lane = threadIdx.x & 63;
  float s = 0.f;
  for (int j = 0; j < 16; j++) {
    int d = lane + j * 64;
    s += x[(size_t)m * DMOD + d] * Wh[d];
  }
  for (int d = 1; d < 64; d <<= 1) s += __shfl_xor(s, d);
  if (lane == 0) out[m] = s + bh[0];
}

extern "C" void kernel_launch(void* const* d_in, const int* in_sizes, int n_in,
                              void* d_out, int out_size, void* d_ws, size_t ws_size,
                              hipStream_t stream) {
  (void)in_sizes; (void)n_in; (void)out_size;
  const float* tokens = (const float*)d_in[0];
  const float* Win    = (const float*)d_in[1];
  const float* binp   = (const float*)d_in[2];
  const float* pos    = (const float*)d_in[3];
  const float* Wq     = (const float*)d_in[4];
  const float* bq     = (const float*)d_in[5];
  const float* Wk     = (const float*)d_in[6];
  const float* bk     = (const float*)d_in[7];
  const float* Wv     = (const float*)d_in[8];
  const float* bv     = (const float*)d_in[9];
  const float* Wo     = (const float*)d_in[10];
  const float* bo     = (const float*)d_in[11];
  const float* W1     = (const float*)d_in[12];
  const float* b1     = (const float*)d_in[13];
  const float* W2     = (const float*)d_in[14];
  const float* b2     = (const float*)d_in[15];
  const float* g1     = (const float*)d_in[16];
  const float* be1    = (const float*)d_in[17];
  const float* g2     = (const float*)d_in[18];
  const float* be2    = (const float*)d_in[19];
  const float* Wh     = (const float*)d_in[20];
  const float* bhp    = (const float*)d_in[21];
  float* out = (float*)d_out;

  char* p = (char*)d_ws;
  auto alloc = [&](size_t bytes) { char* r = p; p += (bytes + 255) & ~(size_t)255; return r; };
  float* xf   = (float*)alloc((size_t)MROWS * DMOD * 4);
  bf16*  xb   = (bf16*) alloc((size_t)MROWS * DMOD * 2);
  float* x2f  = (float*)alloc((size_t)MROWS * DMOD * 4);
  bf16*  x2b  = (bf16*) alloc((size_t)MROWS * DMOD * 2);
  bf16*  tmpb = (bf16*) alloc((size_t)2 * MROWS * DMOD * 2);   // bf16 split-K partials
  bf16*  qb   = (bf16*) alloc((size_t)MROWS * DMOD * 2);
  bf16*  kb   = (bf16*) alloc((size_t)MROWS * DMOD * 2);
  bf16*  vt   = (bf16*) alloc((size_t)MROWS * DMOD * 2);
  bf16*  ob   = (bf16*) alloc((size_t)MROWS * DMOD * 2);
  bf16*  hb   = (bf16*) alloc((size_t)MROWS * FDIM * 2);
  bf16*  tokb = (bf16*) alloc((size_t)MROWS * KPAD * 2);
  bf16*  winb = (bf16*) alloc((size_t)DMOD * KPAD * 2);
  float2* rope2 = (float2*)alloc((size_t)S_LEN * 32 * 8);
  bf16*  pO   = (bf16*) alloc((size_t)32 * NITEM * 2048 * 2);  // 10.5 MB partial O (bf16)
  float* pML  = (float*)alloc((size_t)32 * NITEM * 64 * 4);    // 0.66 MB partial m/l

  size_t used = (size_t)(p - (char*)d_ws);
  bool big = (ws_size - used) >= (size_t)NLAYER * LW_ * 2 + 1024;
  int nlayConv = big ? NLAYER : 1;
  bf16* wb = (bf16*)alloc((size_t)nlayConv * LW_ * 2);

  rope_table<<<(S_LEN * 32 + 255) / 256, 256, 0, stream>>>(rope2);
  pad_cvt<<<(MROWS * KPAD + 255) / 256, 256, 0, stream>>>(tokens, tokb, MROWS);
  pad_cvt<<<(DMOD * KPAD + 255) / 256, 256, 0, stream>>>(Win, winb, DMOD);
  if (big)
    f2b_all<<<2048, 256, 0, stream>>>(          // 64 chunks x 32 blocks
        (const float4*)Wq, (const float4*)Wk, (const float4*)Wv,
        (const float4*)Wo, (const float4*)W1, (const float4*)W2,
        (ushort4*)wb, NLAYER);

  // embed GEMM: x = tokens @ Win^T + bin + pos  (M=2048, N=1024, K=192)
  gemm64<3, 1><<<256, 256, 0, stream>>>(
      tokb, winb, binp, pos, nullptr, nullptr,
      xf, xb, nullptr, nullptr, DMOD, KPAD, 32);

  for (int l = 0; l < NLAYER; l++) {
    if (!big)
      f2b_all<<<2048, 256, 0, stream>>>(        // 8 chunks x 256 blocks
          (const float4*)(Wq + l * DD_), (const float4*)(Wk + l * DD_),
          (const float4*)(Wv + l * DD_), (const float4*)(Wo + l * DD_),
          (const float4*)(W1 + l * FD_), (const float4*)(W2 + l * FD_),
          (ushort4*)wb, 1);
    bf16* wbl = big ? wb + (size_t)l * LW_ : wb;

    // fused QKV GEMM (N=3072): 24x32 = 768 blocks = 3/CU
    gemm64<0, 1><<<768, 256, 0, stream>>>(
        xb, wbl, bq + l * DMOD, bk + l * DMOD, bv + l * DMOD, rope2,
        nullptr, qb, kb, vt, 3 * DMOD, DMOD, 32);

    flash_part<<<640, 256, 0, stream>>>(qb, kb, vt, pO, pML, ob);
    flash_merge<<<768, 256, 0, stream>>>(pO, pML, ob);

    // Wo: split-K2 -> 512 blocks, bf16 partials
    gemm64<1, 2><<<512, 256, 0, stream>>>(
        ob, wbl + 3 * DD_, bo + l * DMOD, nullptr, nullptr, nullptr,
        nullptr, tmpb, nullptr, nullptr, DMOD, DMOD, 32);

    ln_kernel<<<MROWS, 256, 0, stream>>>(xf, tmpb, tmpb + (size_t)MROWS * DMOD,
                                         g1 + l * DMOD, be1 + l * DMOD, x2f, x2b);

    // FFN1 (N=2048): 512 blocks
    gemm64<2, 1><<<512, 256, 0, stream>>>(
        x2b, wbl + 4 * DD_, b1 + l * FDIM, nullptr, nullptr, nullptr,
        nullptr, hb, nullptr, nullptr, FDIM, DMOD, 32);

    // FFN2: split-K2 over K=2048 -> 512 blocks, bf16 partials
    gemm64<1, 2><<<512, 256, 0, stream>>>(
        hb, wbl + 4 * DD_ + FD_, b2 + l * DMOD, nullptr, nullptr, nullptr,
        nullptr, tmpb, nullptr, nullptr, DMOD, FDIM, 32);

    ln_kernel<<<MROWS, 256, 0, stream>>>(x2f, tmpb, tmpb + (size_t)MROWS * DMOD,
                                         g2 + l * DMOD, be2 + l * DMOD, xf, xb);
  }

  head_kernel<<<MROWS / 4, 256, 0, stream>>>(xf, Wh, bhp, out);
}

// Round 18
// 1339.671 us; speedup vs baseline: 1.0203x; 1.0203x over previous
//
#include <hip/hip_runtime.h>
#include <hip/hip_bf16.h>

typedef __hip_bfloat16 bf16;
typedef float f32x4 __attribute__((ext_vector_type(4)));
typedef float f32x16 __attribute__((ext_vector_type(16)));
typedef short s16x8 __attribute__((ext_vector_type(8)));
typedef int i32x4 __attribute__((ext_vector_type(4)));
typedef unsigned u32x2 __attribute__((ext_vector_type(2)));

#define S_LEN 1024
#define BATCH 2
#define TDIM 138
#define KPAD 192
#define DMOD 1024
#define NHEAD 16
#define DHEAD 64
#define NLAYER 8
#define FDIM 2048
#define MROWS 2048
#define NITEM 80             // flash items per bh (256-key chunks)
static const size_t DD_ = (size_t)DMOD * DMOD;   // 1M elems
static const size_t FD_ = (size_t)FDIM * DMOD;   // 2M elems
static const size_t LW_ = 4 * DD_ + 2 * FD_;     // 8M elems per layer

__device__ __forceinline__ void load_lds16(const bf16* g, bf16* l) {
  __builtin_amdgcn_global_load_lds((const __attribute__((address_space(1))) void*)g,
                                   (__attribute__((address_space(3))) void*)l, 16, 0, 0);
}

__device__ __forceinline__ unsigned pack2(float a, float b) {
  unsigned x = __builtin_bit_cast(unsigned short, __float2bfloat16(a));
  unsigned y = __builtin_bit_cast(unsigned short, __float2bfloat16(b));
  return x | (y << 16);
}

__device__ __forceinline__ float b2f(unsigned short u) {
  return __bfloat162float(__builtin_bit_cast(bf16, u));
}

__device__ __forceinline__ int chunk_start(int c) {
  return c == 0 ? 0 : (c == 1 ? 32 : (c == 2 ? 56 : 72));
}

// ---------------- weight f32 -> bf16 convert (grid-stride float4: best measured) ----------------
__global__ __launch_bounds__(256) void f2b_all(
    const float4* __restrict__ Wq, const float4* __restrict__ Wk,
    const float4* __restrict__ Wv, const float4* __restrict__ Wo,
    const float4* __restrict__ W1, const float4* __restrict__ W2,
    ushort4* __restrict__ dst, int nlay) {
  const int DD4 = (int)(DD_ / 4), FD4 = (int)(FD_ / 4), LW4 = 4 * DD4 + 2 * FD4;
  int total = nlay * LW4;
  for (int i = blockIdx.x * 256 + threadIdx.x; i < total; i += gridDim.x * 256) {
    int l = i / LW4, off = i - l * LW4;
    const float4* src; int o2;
    if (off < 3 * DD4) {
      int w = off / DD4; o2 = off - w * DD4 + l * DD4;
      src = w == 0 ? Wq : (w == 1 ? Wk : Wv);
    } else if (off < 4 * DD4) { src = Wo; o2 = off - 3 * DD4 + l * DD4; }
    else if (off < 4 * DD4 + FD4) { src = W1; o2 = off - 4 * DD4 + l * FD4; }
    else { src = W2; o2 = off - 4 * DD4 - FD4 + l * FD4; }
    float4 v = src[o2];
    ushort4 o;
    o.x = __builtin_bit_cast(unsigned short, __float2bfloat16(v.x));
    o.y = __builtin_bit_cast(unsigned short, __float2bfloat16(v.y));
    o.z = __builtin_bit_cast(unsigned short, __float2bfloat16(v.z));
    o.w = __builtin_bit_cast(unsigned short, __float2bfloat16(v.w));
    dst[i] = o;
  }
}

// ---------------- pad+convert a row-major f32 [R][TDIM] -> bf16 [R][KPAD] ----------------
__global__ __launch_bounds__(256) void pad_cvt(const float* __restrict__ in,
                                               bf16* __restrict__ out, int R) {
  int i = blockIdx.x * 256 + threadIdx.x;
  if (i >= R * KPAD) return;
  int r = i / KPAD, t = i - r * KPAD;
  out[i] = __float2bfloat16(t < TDIM ? in[r * TDIM + t] : 0.0f);
}

// ---------------- rope table ----------------
__global__ __launch_bounds__(256) void rope_table(float2* __restrict__ t) {
  int idx = blockIdx.x * 256 + threadIdx.x;
  if (idx >= S_LEN * 32) return;
  int s = idx >> 5, i = idx & 31;
  float freq = __expf(-(float)i * (2.0f / (float)DHEAD) * 9.210340371976184f);
  float sn, cs;
  sincosf((float)s * freq, &sn, &cs);
  t[idx] = make_float2(cs, sn);
}

// ---------------- 64x128 NT GEMM: BK=64, XOR-swizzled LDS, 2-phase dbuf ----------------
template<int EPI, int SPLITK>
__global__ __launch_bounds__(256) void gemm64(
    const bf16* __restrict__ A, const bf16* __restrict__ W,
    const float* __restrict__ b0p, const float* __restrict__ b1p, const float* __restrict__ b2p,
    const float2* __restrict__ rope2, float* __restrict__ Cf,
    bf16* __restrict__ Cb0, bf16* __restrict__ Cb1, bf16* __restrict__ Cb2,
    int N, int K, int nby) {
  constexpr int ASZ = 64 * 64, BSZ = 128 * 64;
  __shared__ bf16 As[2 * ASZ];    // 16 KB
  __shared__ bf16 Bs[2 * BSZ];    // 32 KB
  int nwg = gridDim.x, bid = blockIdx.x;
  int x = bid & 7, c = bid >> 3;                  // XCD, per-XCD index
  int chunkSz = nwg >> 3;
  int bxc = chunkSz / nby;                        // bx2 values per XCD
  int per = 8 * bxc;                              // blocks per by-group stripe
  int grp = c / per, r0_ = c - grp * per;
  int bxl = r0_ >> 3, byg = r0_ & 7;
  int by = grp * 8 + byg;
  int bx2 = x * bxc + bxl;
  int nbx = N >> 7;
  int kh = 0, bx = bx2;
  if constexpr (SPLITK == 2) { bx = bx2 % nbx; kh = bx2 / nbx; }
  int bn = bx * 128, bm = by * 64;
  int Kh = K / SPLITK, koff = kh * Kh;
  int tid = threadIdx.x, lane = tid & 63, w = tid >> 6;
  int lo = lane & 15, hi = lane >> 4;
  int wr = (w >> 1) * 32, wc = (w & 1) * 64;
  f32x4 acc[2][4] = {};

  int srow = tid >> 3;                  // 0..31
  int scol = (tid & 7) * 8;             // elems, 16B chunks
  int scolsw = scol ^ ((srow & 7) << 3);
  const bf16* gA = A + (size_t)(bm + srow) * K + koff + scolsw;
  const bf16* gB = W + (size_t)(bn + srow) * K + koff + scolsw;
  bf16* lA = As + srow * 64 + scol;
  bf16* lB = Bs + srow * 64 + scol;

  auto STAGE = [&](int k0, int b) {
    load_lds16(gA + k0, lA + b * ASZ);
    load_lds16(gA + (size_t)32 * K + k0, lA + b * ASZ + 32 * 64);
    load_lds16(gB + k0, lB + b * BSZ);
    load_lds16(gB + (size_t)32 * K + k0, lB + b * BSZ + 32 * 64);
    load_lds16(gB + (size_t)64 * K + k0, lB + b * BSZ + 64 * 64);
    load_lds16(gB + (size_t)96 * K + k0, lB + b * BSZ + 96 * 64);
  };

  int nt = Kh / 64;
  STAGE(0, 0);
  __syncthreads();
  int cur = 0;
  int rsw = (lo & 7) << 3;              // ds_read swizzle term (row&7 == lo&7)
  for (int t = 0; t < nt; t++) {
    if (t + 1 < nt) STAGE((t + 1) * 64, cur ^ 1);
    const bf16* Ab = As + cur * ASZ;
    const bf16* Bb = Bs + cur * BSZ;
#pragma unroll
    for (int ks = 0; ks < 2; ks++) {
      int col = ((ks * 32 + hi * 8) ^ rsw);
      s16x8 af[2], bfr[4];
#pragma unroll
      for (int mi = 0; mi < 2; mi++) af[mi] = *(const s16x8*)(Ab + (wr + mi * 16 + lo) * 64 + col);
#pragma unroll
      for (int nj = 0; nj < 4; nj++) bfr[nj] = *(const s16x8*)(Bb + (wc + nj * 16 + lo) * 64 + col);
#pragma unroll
      for (int mi = 0; mi < 2; mi++)
#pragma unroll
        for (int nj = 0; nj < 4; nj++)
          acc[mi][nj] = __builtin_amdgcn_mfma_f32_16x16x32_bf16(af[mi], bfr[nj], acc[mi][nj], 0, 0, 0);
    }
    __syncthreads();
    cur ^= 1;
  }

#pragma unroll
  for (int mi = 0; mi < 2; mi++)
#pragma unroll
    for (int nj = 0; nj < 4; nj++)
#pragma unroll
      for (int r = 0; r < 4; r++) {
        int m = bm + wr + mi * 16 + hi * 4 + r;
        int n = bn + wc + nj * 16 + lo;
        float v = acc[mi][nj][r];
        if constexpr (EPI == 0) {
          int which = n >> 10;
          int d = n & 1023, h = d >> 6, dh = d & 63;
          int s = m >> 1, bb = m & 1;
          const float* bp = which == 0 ? b0p : (which == 1 ? b1p : b2p);
          v += bp[d];
          if (which < 2) {
            float pv = __shfl_xor(v, 1);
            float2 cn = rope2[s * 32 + (dh >> 1)];
            float o = (dh & 1) ? (v * cn.x + pv * cn.y) : (v * cn.x - pv * cn.y);
            bf16* dst = which == 0 ? Cb0 : Cb1;
            dst[(((size_t)(bb * NHEAD + h)) * S_LEN + s) * DHEAD + dh] = __float2bfloat16(o);
          } else {
            Cb2[(((size_t)(bb * NHEAD + h)) * DHEAD + dh) * S_LEN + s] = __float2bfloat16(v);
          }
        } else if constexpr (EPI == 1) {
          if (SPLITK == 1 || kh == 0) v += b0p[n];
          Cb0[((size_t)kh * MROWS + m) * N + n] = __float2bfloat16(v);
        } else if constexpr (EPI == 2) {
          Cb0[(size_t)m * N + n] = __float2bfloat16(fmaxf(v + b0p[n], 0.0f));
        } else {
          float v2 = v + b0p[n] + b1p[(size_t)(m >> 1) * DMOD + n];
          Cf[(size_t)m * N + n] = v2;
          Cb0[(size_t)m * N + n] = __float2bfloat16(v2);
        }
      }
}

// ---------------- split-K flash attention, 32x32 MFMA, XCD-affine, 256-key chunks ----------------
__global__ __launch_bounds__(256) void flash_part(const bf16* __restrict__ Q,
    const bf16* __restrict__ K, const bf16* __restrict__ Vt,
    bf16* __restrict__ pO, float* __restrict__ pML, bf16* __restrict__ O) {
  int bid = blockIdx.x;                    // 640 = 8 xcd * 4 bh * 20 blocks
  int xcd = bid & 7, idx = bid >> 3;       // idx in [0,80)
  int bh = xcd * 4 + idx / 20;
  int w = threadIdx.x >> 6, lane = threadIdx.x & 63;
  int widx = (idx % 20) * 4 + w;           // item in [0,80)
  int c = widx < 32 ? 0 : (widx < 56 ? 1 : (widx < 72 ? 2 : 3));
  int qt = widx - chunk_start(c) + 8 * c;  // q-tile [0,32)
  int l31 = lane & 31, hi1 = lane >> 5;
  int q0 = qt * 32, kc0 = c * 256;
  int kend = min(kc0 + 256, q0 + 32);
  int nkt = (kend - kc0 + 31) >> 5;        // 1..8

  const size_t qkb = (size_t)bh * S_LEN * DHEAD;
  const bf16* qp = Q + qkb + (size_t)(q0 + l31) * DHEAD + hi1 * 8;
  s16x8 bq0 = *(const s16x8*)(qp);
  s16x8 bq1 = *(const s16x8*)(qp + 16);
  s16x8 bq2 = *(const s16x8*)(qp + 32);
  s16x8 bq3 = *(const s16x8*)(qp + 48);
  const bf16* kB = K + qkb;
  const bf16* vB = Vt + qkb;
  f32x16 accO0 = {}, accO1 = {};
  float mv = -INFINITY, lv = 0.0f;
  const float SC = 0.18033688011112042f;   // (1/8) * log2(e)

  auto loadTile = [&](int kc, s16x8& k0, s16x8& k1, s16x8& k2, s16x8& k3,
                      s16x8& v0, s16x8& v1, s16x8& v2, s16x8& v3) {
    const bf16* kp = kB + (size_t)(kc + l31) * DHEAD + hi1 * 8;
    k0 = *(const s16x8*)(kp);
    k1 = *(const s16x8*)(kp + 16);
    k2 = *(const s16x8*)(kp + 32);
    k3 = *(const s16x8*)(kp + 48);
    const bf16* vp = vB + (size_t)l31 * S_LEN + kc + hi1 * 8;
    v0 = *(const s16x8*)(vp);
    v1 = *(const s16x8*)(vp + 16);
    v2 = *(const s16x8*)(vp + (size_t)32 * S_LEN);
    v3 = *(const s16x8*)(vp + (size_t)32 * S_LEN + 16);
  };

  auto computeTile = [&](int kc, s16x8 ka0, s16x8 ka1, s16x8 ka2, s16x8 ka3,
                         s16x8 va00, s16x8 va01, s16x8 va10, s16x8 va11) {
    f32x16 st = {};
    st = __builtin_amdgcn_mfma_f32_32x32x16_bf16(ka0, bq0, st, 0, 0, 0);
    st = __builtin_amdgcn_mfma_f32_32x32x16_bf16(ka1, bq1, st, 0, 0, 0);
    st = __builtin_amdgcn_mfma_f32_32x32x16_bf16(ka2, bq2, st, 0, 0, 0);
    st = __builtin_amdgcn_mfma_f32_32x32x16_bf16(ka3, bq3, st, 0, 0, 0);

    bool diag = (kc >= q0);                // wave-uniform
    float pmax = -INFINITY;
#pragma unroll
    for (int j = 0; j < 16; j++) {
      float s = st[j] * SC;
      if (diag) {
        int krow = kc + (j & 3) + 8 * (j >> 2) + 4 * hi1;
        if (krow > q0 + l31) s = -INFINITY;
      }
      st[j] = s;
      pmax = fmaxf(pmax, s);
    }
    pmax = fmaxf(pmax, __shfl_xor(pmax, 32));
    float mnew = fmaxf(mv, pmax);
    float fs = exp2f(mv - mnew);
    float sum = 0.0f;
#pragma unroll
    for (int j = 0; j < 16; j++) {
      float e = exp2f(st[j] - mnew);
      st[j] = e;
      sum += e;
    }
    sum += __shfl_xor(sum, 32);
    lv = lv * fs + sum;
    mv = mnew;
    accO0 = accO0 * fs;
    accO1 = accO1 * fs;

    unsigned w0 = pack2(st[0], st[1]),   w1 = pack2(st[2], st[3]);
    unsigned w2 = pack2(st[4], st[5]),   w3 = pack2(st[6], st[7]);
    unsigned w4 = pack2(st[8], st[9]),   w5 = pack2(st[10], st[11]);
    unsigned w6 = pack2(st[12], st[13]), w7 = pack2(st[14], st[15]);
    unsigned xw0 = (unsigned)__shfl_xor((int)w0, 32), xw1 = (unsigned)__shfl_xor((int)w1, 32);
    unsigned xw2 = (unsigned)__shfl_xor((int)w2, 32), xw3 = (unsigned)__shfl_xor((int)w3, 32);
    unsigned xw4 = (unsigned)__shfl_xor((int)w4, 32), xw5 = (unsigned)__shfl_xor((int)w5, 32);
    unsigned xw6 = (unsigned)__shfl_xor((int)w6, 32), xw7 = (unsigned)__shfl_xor((int)w7, 32);
    bool hb = (hi1 != 0);
    i32x4 f0, f1;
    f0.x = (int)(hb ? xw2 : w0); f0.y = (int)(hb ? xw3 : w1);
    f0.z = (int)(hb ? w2 : xw0); f0.w = (int)(hb ? w3 : xw1);
    f1.x = (int)(hb ? xw6 : w4); f1.y = (int)(hb ? xw7 : w5);
    f1.z = (int)(hb ? w6 : xw4); f1.w = (int)(hb ? w7 : xw5);
    s16x8 pf0 = __builtin_bit_cast(s16x8, f0);
    s16x8 pf1 = __builtin_bit_cast(s16x8, f1);
    accO0 = __builtin_amdgcn_mfma_f32_32x32x16_bf16(va00, pf0, accO0, 0, 0, 0);
    accO0 = __builtin_amdgcn_mfma_f32_32x32x16_bf16(va01, pf1, accO0, 0, 0, 0);
    accO1 = __builtin_amdgcn_mfma_f32_32x32x16_bf16(va10, pf0, accO1, 0, 0, 0);
    accO1 = __builtin_amdgcn_mfma_f32_32x32x16_bf16(va11, pf1, accO1, 0, 0, 0);
  };

  // 2-deep register pipeline: named sets, unroll-2 rotation (static indexing)
  s16x8 A0, A1, A2, A3, A4, A5, A6, A7;
  s16x8 B0, B1, B2, B3, B4, B5, B6, B7;
  loadTile(kc0, A0, A1, A2, A3, A4, A5, A6, A7);
  for (int kt = 0; kt < nkt; kt += 2) {
    if (kt + 1 < nkt) loadTile(kc0 + (kt + 1) * 32, B0, B1, B2, B3, B4, B5, B6, B7);
    computeTile(kc0 + kt * 32, A0, A1, A2, A3, A4, A5, A6, A7);
    if (kt + 1 < nkt) {
      if (kt + 2 < nkt) loadTile(kc0 + (kt + 2) * 32, A0, A1, A2, A3, A4, A5, A6, A7);
      computeTile(kc0 + (kt + 1) * 32, B0, B1, B2, B3, B4, B5, B6, B7);
    }
  }

  if (widx < 8) {
    // single-chunk item: write normalized O directly, skip partials+merge
    int b = bh >> 4, h = bh & 15;
    float linv = 1.0f / lv;
    bf16* po = O + ((size_t)(q0 + l31) * BATCH + b) * DMOD + h * DHEAD + 4 * hi1;
#pragma unroll
    for (int jj = 0; jj < 4; jj++) {
      u32x2 v0, v1;
      v0.x = pack2(accO0[4 * jj] * linv, accO0[4 * jj + 1] * linv);
      v0.y = pack2(accO0[4 * jj + 2] * linv, accO0[4 * jj + 3] * linv);
      v1.x = pack2(accO1[4 * jj] * linv, accO1[4 * jj + 1] * linv);
      v1.y = pack2(accO1[4 * jj + 2] * linv, accO1[4 * jj + 3] * linv);
      *(u32x2*)(po + 8 * jj) = v0;
      *(u32x2*)(po + 32 + 8 * jj) = v1;
    }
  } else {
    int pbase = bh * NITEM + widx;
    bf16* po = pO + (size_t)pbase * 2048 + l31 * 64 + 4 * hi1;
#pragma unroll
    for (int jj = 0; jj < 4; jj++) {
      u32x2 v0, v1;
      v0.x = pack2(accO0[4 * jj], accO0[4 * jj + 1]);
      v0.y = pack2(accO0[4 * jj + 2], accO0[4 * jj + 3]);
      v1.x = pack2(accO1[4 * jj], accO1[4 * jj + 1]);
      v1.y = pack2(accO1[4 * jj + 2], accO1[4 * jj + 3]);
      *(u32x2*)(po + 8 * jj) = v0;
      *(u32x2*)(po + 32 + 8 * jj) = v1;
    }
    if (hi1 == 0) {
      pML[pbase * 64 + l31] = mv;
      pML[pbase * 64 + 32 + l31] = lv;
    }
  }
}

// ---------------- split-K flash attention, merge (qt in [8,32) only) ----------------
__global__ __launch_bounds__(256) void flash_merge(const bf16* __restrict__ pO,
    const float* __restrict__ pML, bf16* __restrict__ O) {
  int bid = blockIdx.x;                    // 768 = 8 xcd * 4 bh * 24 qt
  int xcd = bid & 7, idx = bid >> 3;
  int bh = xcd * 4 + idx / 24, qt = idx % 24 + 8;
  int b = bh >> 4, h = bh & 15;
  int nch = (qt >> 3) + 1;                 // chunk c serves qt >= 8c
  int t = threadIdx.x;
  int dh = t & 63, r0 = t >> 6;
  int ibase = bh * NITEM;
#pragma unroll
  for (int j = 0; j < 8; j++) {
    int row = j * 4 + r0;
    float ms = -INFINITY;
    for (int cc = 0; cc < nch; cc++) {
      int wi = chunk_start(cc) + qt - 8 * cc;
      ms = fmaxf(ms, pML[(ibase + wi) * 64 + row]);
    }
    float l = 0.0f, o = 0.0f;
    for (int cc = 0; cc < nch; cc++) {
      int wi = chunk_start(cc) + qt - 8 * cc;
      float wgt = exp2f(pML[(ibase + wi) * 64 + row] - ms);
      l += wgt * pML[(ibase + wi) * 64 + 32 + row];
      o += wgt * __bfloat162float(pO[(size_t)(ibase + wi) * 2048 + row * 64 + dh]);
    }
    int q = qt * 32 + row;
    O[((size_t)q * BATCH + b) * DMOD + h * DHEAD + dh] = __float2bfloat16(o / l);
  }
}

// ---------------- LayerNorm(a + r0 + r1) * g + be -> outf/outb (vectorized) ----------------
__global__ __launch_bounds__(256) void ln_kernel(const float* __restrict__ a,
    const bf16* __restrict__ r0, const bf16* __restrict__ r1,
    const float* __restrict__ g, const float* __restrict__ be,
    float* __restrict__ outf, bf16* __restrict__ outb) {
  int m = blockIdx.x;
  int tid = threadIdx.x;
  int d0 = tid * 4;
  size_t base = (size_t)m * DMOD + d0;
  f32x4 av = *(const f32x4*)(a + base);
  ushort4 u0 = *(const ushort4*)(r0 + base);
  ushort4 u1 = *(const ushort4*)(r1 + base);
  float vals[4];
  vals[0] = av[0] + b2f(u0.x) + b2f(u1.x);
  vals[1] = av[1] + b2f(u0.y) + b2f(u1.y);
  vals[2] = av[2] + b2f(u0.z) + b2f(u1.z);
  vals[3] = av[3] + b2f(u0.w) + b2f(u1.w);
  float s1 = vals[0] + vals[1] + vals[2] + vals[3];
  float s2 = vals[0]*vals[0] + vals[1]*vals[1] + vals[2]*vals[2] + vals[3]*vals[3];
  __shared__ float red[8];
  for (int d = 1; d < 64; d <<= 1) { s1 += __shfl_xor(s1, d); s2 += __shfl_xor(s2, d); }
  int w = tid >> 6, lane = tid & 63;
  if (lane == 0) { red[w] = s1; red[4 + w] = s2; }
  __syncthreads();
  s1 = red[0] + red[1] + red[2] + red[3];
  s2 = red[4] + red[5] + red[6] + red[7];
  float mean = s1 * (1.0f / DMOD);
  float var = s2 * (1.0f / DMOD) - mean * mean;
  float rstd = rsqrtf(var + 1e-5f);
  f32x4 gv = *(const f32x4*)(g + d0);
  f32x4 bv = *(const f32x4*)(be + d0);
  f32x4 ov;
  ushort4 ob_;
  float o0 = (vals[0] - mean) * rstd * gv[0] + bv[0];
  float o1 = (vals[1] - mean) * rstd * gv[1] + bv[1];
  float o2 = (vals[2] - mean) * rstd * gv[2] + bv[2];
  float o3 = (vals[3] - mean) * rstd * gv[3] + bv[3];
  ov[0] = o0; ov[1] = o1; ov[2] = o2; ov[3] = o3;
  ob_.x = __builtin_bit_cast(unsigned short, __float2bfloat16(o0));
  ob_.y = __builtin_bit_cast(unsigned short, __float2bfloat16(o1));
  ob_.z = __builtin_bit_cast(unsigned short, __float2bfloat16(o2));
  ob_.w = __builtin_bit_cast(unsigned short, __float2bfloat16(o3));
  *(f32x4*)(outf + base) = ov;
  *(ushort4*)(outb + base) = ob_;
}

// ---------------- head ----------------
__global__ __launch_bounds__(256) void head_kernel(const float* __restrict__ x,
    const float* __restrict__ Wh, const float* __restrict__ bh, float* __restrict__ out) {
  int m = blockIdx.x * 4 + (threadIdx.x >> 6);
  int lane = threadIdx.x & 63;
  float s = 0.f;
  for (int j = 0; j < 16; j++) {
    int d = lane + j * 64;
    s += x[(size_t)m * DMOD + d] * Wh[d];
  }
  for (int d = 1; d < 64; d <<= 1) s += __shfl_xor(s, d);
  if (lane == 0) out[m] = s + bh[0];
}

extern "C" void kernel_launch(void* const* d_in, const int* in_sizes, int n_in,
                              void* d_out, int out_size, void* d_ws, size_t ws_size,
                              hipStream_t stream) {
  (void)in_sizes; (void)n_in; (void)out_size;
  const float* tokens = (const float*)d_in[0];
  const float* Win    = (const float*)d_in[1];
  const float* binp   = (const float*)d_in[2];
  const float* pos    = (const float*)d_in[3];
  const float* Wq     = (const float*)d_in[4];
  const float* bq     = (const float*)d_in[5];
  const float* Wk     = (const float*)d_in[6];
  const float* bk     = (const float*)d_in[7];
  const float* Wv     = (const float*)d_in[8];
  const float* bv     = (const float*)d_in[9];
  const float* Wo     = (const float*)d_in[10];
  const float* bo     = (const float*)d_in[11];
  const float* W1     = (const float*)d_in[12];
  const float* b1     = (const float*)d_in[13];
  const float* W2     = (const float*)d_in[14];
  const float* b2     = (const float*)d_in[15];
  const float* g1     = (const float*)d_in[16];
  const float* be1    = (const float*)d_in[17];
  const float* g2     = (const float*)d_in[18];
  const float* be2    = (const float*)d_in[19];
  const float* Wh     = (const float*)d_in[20];
  const float* bhp    = (const float*)d_in[21];
  float* out = (float*)d_out;

  char* p = (char*)d_ws;
  auto alloc = [&](size_t bytes) { char* r = p; p += (bytes + 255) & ~(size_t)255; return r; };
  float* xf   = (float*)alloc((size_t)MROWS * DMOD * 4);
  bf16*  xb   = (bf16*) alloc((size_t)MROWS * DMOD * 2);
  float* x2f  = (float*)alloc((size_t)MROWS * DMOD * 4);
  bf16*  x2b  = (bf16*) alloc((size_t)MROWS * DMOD * 2);
  bf16*  tmpb = (bf16*) alloc((size_t)2 * MROWS * DMOD * 2);   // bf16 split-K partials
  bf16*  qb   = (bf16*) alloc((size_t)MROWS * DMOD * 2);
  bf16*  kb   = (bf16*) alloc((size_t)MROWS * DMOD * 2);
  bf16*  vt   = (bf16*) alloc((size_t)MROWS * DMOD * 2);
  bf16*  ob   = (bf16*) alloc((size_t)MROWS * DMOD * 2);
  bf16*  hb   = (bf16*) alloc((size_t)MROWS * FDIM * 2);
  bf16*  tokb = (bf16*) alloc((size_t)MROWS * KPAD * 2);
  bf16*  winb = (bf16*) alloc((size_t)DMOD * KPAD * 2);
  float2* rope2 = (float2*)alloc((size_t)S_LEN * 32 * 8);
  bf16*  pO   = (bf16*) alloc((size_t)32 * NITEM * 2048 * 2);  // 10.5 MB partial O (bf16)
  float* pML  = (float*)alloc((size_t)32 * NITEM * 64 * 4);    // 0.66 MB partial m/l

  size_t used = (size_t)(p - (char*)d_ws);
  bool big = (ws_size - used) >= (size_t)NLAYER * LW_ * 2 + 1024;
  int nlayConv = big ? NLAYER : 1;
  bf16* wb = (bf16*)alloc((size_t)nlayConv * LW_ * 2);

  rope_table<<<(S_LEN * 32 + 255) / 256, 256, 0, stream>>>(rope2);
  pad_cvt<<<(MROWS * KPAD + 255) / 256, 256, 0, stream>>>(tokens, tokb, MROWS);
  pad_cvt<<<(DMOD * KPAD + 255) / 256, 256, 0, stream>>>(Win, winb, DMOD);
  if (big)
    f2b_all<<<2048, 256, 0, stream>>>(
        (const float4*)Wq, (const float4*)Wk, (const float4*)Wv,
        (const float4*)Wo, (const float4*)W1, (const float4*)W2,
        (ushort4*)wb, NLAYER);

  // embed GEMM: x = tokens @ Win^T + bin + pos  (M=2048, N=1024, K=192)
  gemm64<3, 1><<<256, 256, 0, stream>>>(
      tokb, winb, binp, pos, nullptr, nullptr,
      xf, xb, nullptr, nullptr, DMOD, KPAD, 32);

  for (int l = 0; l < NLAYER; l++) {
    if (!big)
      f2b_all<<<2048, 256, 0, stream>>>(
          (const float4*)(Wq + l * DD_), (const float4*)(Wk + l * DD_),
          (const float4*)(Wv + l * DD_), (const float4*)(Wo + l * DD_),
          (const float4*)(W1 + l * FD_), (const float4*)(W2 + l * FD_),
          (ushort4*)wb, 1);
    bf16* wbl = big ? wb + (size_t)l * LW_ : wb;

    // fused QKV GEMM (N=3072): 24x32 = 768 blocks = 3/CU
    gemm64<0, 1><<<768, 256, 0, stream>>>(
        xb, wbl, bq + l * DMOD, bk + l * DMOD, bv + l * DMOD, rope2,
        nullptr, qb, kb, vt, 3 * DMOD, DMOD, 32);

    flash_part<<<640, 256, 0, stream>>>(qb, kb, vt, pO, pML, ob);
    flash_merge<<<768, 256, 0, stream>>>(pO, pML, ob);

    // Wo: split-K2 -> 512 blocks, bf16 partials
    gemm64<1, 2><<<512, 256, 0, stream>>>(
        ob, wbl + 3 * DD_, bo + l * DMOD, nullptr, nullptr, nullptr,
        nullptr, tmpb, nullptr, nullptr, DMOD, DMOD, 32);

    ln_kernel<<<MROWS, 256, 0, stream>>>(xf, tmpb, tmpb + (size_t)MROWS * DMOD,
                                         g1 + l * DMOD, be1 + l * DMOD, x2f, x2b);

    // FFN1 (N=2048): 512 blocks
    gemm64<2, 1><<<512, 256, 0, stream>>>(
        x2b, wbl + 4 * DD_, b1 + l * FDIM, nullptr, nullptr, nullptr,
        nullptr, hb, nullptr, nullptr, FDIM, DMOD, 32);

    // FFN2: split-K2 over K=2048 -> 512 blocks, bf16 partials
    gemm64<1, 2><<<512, 256, 0, stream>>>(
        hb, wbl + 4 * DD_ + FD_, b2 + l * DMOD, nullptr, nullptr, nullptr,
        nullptr, tmpb, nullptr, nullptr, DMOD, FDIM, 32);

    ln_kernel<<<MROWS, 256, 0, stream>>>(x2f, tmpb, tmpb + (size_t)MROWS * DMOD,
                                         g2 + l * DMOD, be2 + l * DMOD, xf, xb);
  }

  head_kernel<<<MROWS / 4, 256, 0, stream>>>(xf, Wh, bhp, out);
}